// Round 1
// baseline (1003.356 us; speedup 1.0000x reference)
//
#include <hip/hip_runtime.h>

// out[b,c,w,x,v] = sum_i x[b,c,w,x,v,i] * a[b,c,i]
// B=128, C=128, X=3, Y=16  -> rows per (b,c) = 3*16*16 = 768, row length = 16.
// Pure HBM stream: x = 805 MB read, out = 50 MB write, a = 1 MB (L2-resident).

constexpr int ROWS_PER_BC = 3 * 16 * 16;  // 768
constexpr int YN = 16;

__global__ __launch_bounds__(256) void feat_contract_kernel(
    const float* __restrict__ x,
    const float* __restrict__ na,
    float* __restrict__ out) {
    const int bc = blockIdx.y;                                   // (b,c) flat index
    const int r  = blockIdx.x * blockDim.x + threadIdx.x;        // 0..767 row in slice

    // a[b,c,0:16] — address is uniform across the block (depends only on blockIdx.y),
    // so this is one broadcast/scalar load serving all 768 outputs of the slice.
    const float4* __restrict__ arow =
        reinterpret_cast<const float4*>(na + (size_t)bc * YN);
    const float4 a0 = arow[0];
    const float4 a1 = arow[1];
    const float4 a2 = arow[2];
    const float4 a3 = arow[3];

    // x row: 16 contiguous floats = 4x float4. Lanes r, r+1, ... read consecutive
    // 64 B rows -> wave issues contiguous 4 KB of global_load_dwordx4.
    const size_t row = (size_t)bc * ROWS_PER_BC + r;
    const float4* __restrict__ xr =
        reinterpret_cast<const float4*>(x + row * YN);
    const float4 x0 = xr[0];
    const float4 x1 = xr[1];
    const float4 x2 = xr[2];
    const float4 x3 = xr[3];

    float s = x0.x * a0.x + x0.y * a0.y + x0.z * a0.z + x0.w * a0.w;
    s += x1.x * a1.x + x1.y * a1.y + x1.z * a1.z + x1.w * a1.w;
    s += x2.x * a2.x + x2.y * a2.y + x2.z * a2.z + x2.w * a2.w;
    s += x3.x * a3.x + x3.y * a3.y + x3.z * a3.z + x3.w * a3.w;

    out[row] = s;
}

extern "C" void kernel_launch(void* const* d_in, const int* in_sizes, int n_in,
                              void* d_out, int out_size, void* d_ws, size_t ws_size,
                              hipStream_t stream) {
    const float* x  = (const float*)d_in[0];   // [B,C,3,16,16,16] f32
    const float* na = (const float*)d_in[1];   // [B,C,16] f32
    float* out = (float*)d_out;                // [B,C,3,16,16] f32

    const int BC = in_sizes[1] / YN;           // B*C = 16384
    // 768 rows per (b,c) -> 3 blocks of 256 threads in x, one (b,c) per y.
    dim3 grid(ROWS_PER_BC / 256, BC);
    dim3 block(256);
    feat_contract_kernel<<<grid, block, 0, stream>>>(x, na, out);
}

// Round 2
// 984.671 us; speedup vs baseline: 1.0190x; 1.0190x over previous
//
#include <hip/hip_runtime.h>

// out[b,c,w,x,v] = sum_i x[b,c,w,x,v,i] * a[b,c,i]
// B=128, C=128, X=3, Y=16 -> rows per (b,c) = 768, row length 16 floats (64 B).
// HBM stream: x = 805 MB read, out = 50 MB write, a = 1 MB (L2-resident).
// Floor: 855 MB / 6.3 TB/s ~= 136 us.
//
// Access pattern: 4 lanes cooperate per row. Lane t loads the float4 at
// byte offset t*16 within the wave's 1 KB window -> perfectly contiguous
// global_load_dwordx4 per instruction (same pattern as the 6.29 TB/s
// float4-copy ubench). Quad reduce via __shfl_xor (DPP), lane q==0 stores
// (active lanes write contiguous 4 B addresses).

constexpr int ROWS_PER_BC = 3 * 16 * 16;  // 768
constexpr int YN = 16;

__global__ __launch_bounds__(256) void feat_contract_kernel(
    const float* __restrict__ x,
    const float* __restrict__ na,
    float* __restrict__ out) {
    const int bc = blockIdx.y;
    const int t  = threadIdx.x;            // 0..255
    const int q  = t & 3;                  // quarter of the row (0..3)
    const int lr = t >> 2;                 // local row 0..63 within block
    const int row_in_slice = blockIdx.x * 64 + lr;     // 0..767

    // a quarter: na[bc*16 + q*4 .. +4) — 4 distinct broadcast addrs per wave,
    // 1 MB array, L2-resident.
    const float4 aq = *reinterpret_cast<const float4*>(na + (size_t)bc * YN + q * 4);

    // x quarter-row: addr = slice_base + row*64B + q*16B = wave_base + lane*16B
    // -> fully contiguous 1 KB per wave per instruction.
    const size_t row = (size_t)bc * ROWS_PER_BC + row_in_slice;
    const float4 xq = *reinterpret_cast<const float4*>(x + row * YN + q * 4);

    float s = xq.x * aq.x + xq.y * aq.y + xq.z * aq.z + xq.w * aq.w;

    // reduce across the quad (lanes t^1, t^2) — DPP quad_perm, no LDS.
    s += __shfl_xor(s, 1, 64);
    s += __shfl_xor(s, 2, 64);

    if (q == 0) {
        // active lanes 0,4,8,... store contiguous 4 B addresses -> coalesced.
        out[row] = s;
    }
}

extern "C" void kernel_launch(void* const* d_in, const int* in_sizes, int n_in,
                              void* d_out, int out_size, void* d_ws, size_t ws_size,
                              hipStream_t stream) {
    const float* x  = (const float*)d_in[0];   // [B,C,3,16,16,16] f32
    const float* na = (const float*)d_in[1];   // [B,C,16] f32
    float* out = (float*)d_out;                // [B,C,3,16,16] f32

    const int BC = in_sizes[1] / YN;           // B*C = 16384
    // 768 rows per (b,c), 64 rows per 256-thread block -> 12 blocks in x.
    dim3 grid(ROWS_PER_BC / 64, BC);
    dim3 block(256);
    feat_contract_kernel<<<grid, block, 0, stream>>>(x, na, out);
}